// Round 4
// baseline (189.808 us; speedup 1.0000x reference)
//
#include <hip/hip_runtime.h>

// out = softmax((x@Wq+bq)(x@Wk+bk)^T / sqrt(128)) @ (x@Wv+bv), N=8192, fp32.
//
// Round 8:
//  - k_flash: 512-thread blocks, 8 waves = 2 key-groups (kg) x 4 q-groups (qg).
//    Per-wave shape identical to round-6 (q2=2, 32 keys = former kb loop pinned
//    to kg) so VGPR ~92 -> 4 waves/SIMD at 2 blocks/CU (LDS exactly 80KB,
//    launch_bounds(512,4)). Round-6 audit: LDS pipe ~51% busy, ~49% idle at
//    2 waves/SIMD (serial QK->exp2->pack->PV chain uncovered). Same LDS traffic
//    per work, all round-6/7 proven swizzles reused; cross-kg O/l reduction once
//    per block via reused LDS (linear lane layout, conflict-free).
//    Round-7 lesson: V tile MUST keep XOR swizzle (64B rows -> 8-way without).
//  - k_qkv: round-4 shape (M-tile 64, grid (128,3)) - staging-volume optimal.
//  - k_build_wt: coalesced LDS-transpose of W -> wt bf16 [3][128][1024]; Wv pre-scaled 1/16.
//  - softmax shift-free (|s|<=5.4 so exp2 never overflows); sp fastest -> XCD-pinned K/V.
//  - k_merge: out = 16 * sum(opart) / sum(l)   (16 undoes the V/16 scaling).

typedef __attribute__((ext_vector_type(8))) short bf16x8;
typedef __attribute__((ext_vector_type(4))) float f32x4;

#define NTOK 8192
#define DMODEL 1024
#define DH 128
#define NSPLIT 8
#define CPS 16  // chunks (of 64 keys) per split

__device__ __forceinline__ unsigned short f2bf(float f) {
  unsigned int u = __builtin_bit_cast(unsigned int, f);
  u += 0x7fffu + ((u >> 16) & 1u);
  return (unsigned short)(u >> 16);
}

__device__ __forceinline__ unsigned int pack2bf(float a, float b) {
  return (unsigned int)f2bf(a) | ((unsigned int)f2bf(b) << 16);
}

__device__ __forceinline__ void gl2lds16(const void* gp, void* lp) {
  const __attribute__((address_space(1))) unsigned int* g =
      (const __attribute__((address_space(1))) unsigned int*)gp;
  __attribute__((address_space(3))) unsigned int* l =
      (__attribute__((address_space(3))) unsigned int*)lp;
  __builtin_amdgcn_global_load_lds(g, l, 16, 0, 0);
}

// ------------------- W [1024][128] -> wt bf16 [128][1024], coalesced transpose
__global__ __launch_bounds__(256) void k_build_wt(const float* __restrict__ Wq,
                                                  const float* __restrict__ Wk,
                                                  const float* __restrict__ Wv,
                                                  unsigned short* __restrict__ wt) {
  __shared__ unsigned short tile[32 * 130];
  int k0 = blockIdx.x * 32;  // grid (32, 3)
  int p = blockIdx.y;
  int t = threadIdx.x;
  const float* W = (p == 0) ? Wq : ((p == 1) ? Wk : Wv);
  float vscale = (p == 2) ? 0.0625f : 1.0f;  // V/16: bounds fp16 partials; merge x16
#pragma unroll
  for (int i = 0; i < 16; i++) {
    int e = i * 256 + t;
    int n = e & 127, kk = e >> 7;
    tile[kk * 130 + n] = f2bf(W[(size_t)(k0 + kk) * DH + n] * vscale);
  }
  __syncthreads();
#pragma unroll
  for (int i = 0; i < 16; i++) {
    int e = i * 256 + t;
    int kk = e & 31, n = e >> 5;
    wt[(size_t)(p * DH + n) * DMODEL + k0 + kk] = tile[kk * 130 + n];
  }
}

// ------------------------------- QKV GEMM, dbuf single-barrier, x fp32 in LDS
// grid (128, 3), block 256. M-tile 64, N=128, BK=64.  (round-4 shape)
__global__ __launch_bounds__(256, 2) void k_qkv(const float* __restrict__ x,
                                                const unsigned short* __restrict__ wt,
                                                const float* __restrict__ bq,
                                                const float* __restrict__ bk,
                                                const float* __restrict__ bv,
                                                unsigned short* __restrict__ qs,
                                                unsigned short* __restrict__ kkv,
                                                unsigned short* __restrict__ vt) {
  __shared__ float xt[2][64 * 64];             // fp32 x-tile, XOR-swizzled, 16 KB each
  __shared__ unsigned short wtt[2][128 * 64];  // bf16 W^T tile, XOR-swizzled, 16 KB each
  int mt = blockIdx.x, p = blockIdx.y;
  int tid = threadIdx.x;
  int w = tid >> 6, lane = tid & 63, l16 = lane & 15, g = lane >> 4;

#define STAGE_QKV(buf, k0)                                                     \
  {                                                                            \
    _Pragma("unroll") for (int r = 0; r < 4; r++) {                            \
      int seg = r * 4 + w;                                                     \
      int xr = seg * 4 + (lane >> 4);                                          \
      int xlc = ((lane & 15) ^ (xr & 15)) & 15;                                \
      gl2lds16(&x[(size_t)(mt * 64 + xr) * DMODEL + (k0) + xlc * 4],           \
               &xt[buf][seg * 256]);                                           \
      int wc = seg * 8 + (lane >> 3);                                          \
      int wlc = ((lane & 7) ^ (wc & 7)) & 7;                                   \
      gl2lds16(&wt[(size_t)(p * DH + wc) * DMODEL + (k0) + wlc * 8],           \
               &wtt[buf][seg * 512]);                                          \
    }                                                                          \
  }

  f32x4 zero = {0.f, 0.f, 0.f, 0.f};
  f32x4 acc[8];
#pragma unroll
  for (int i = 0; i < 8; i++) acc[i] = zero;

  STAGE_QKV(0, 0);
  int arow = w * 16 + l16;
  for (int kt2 = 0; kt2 < 16; kt2++) {
    int b = kt2 & 1;
    __syncthreads();  // own vmcnt(0) drain -> tiles ready; all waves past prev reads
    if (kt2 < 15) STAGE_QKV(b ^ 1, (kt2 + 1) * 64);

    bf16x8 a[2];
#pragma unroll
    for (int half = 0; half < 2; half++) {
      int lc0 = half * 8 + g * 2;
      const f32x4 u0 = *(const f32x4*)&xt[b][arow * 64 + ((lc0 ^ l16) & 15) * 4];
      const f32x4 u1 = *(const f32x4*)&xt[b][arow * 64 + (((lc0 + 1) ^ l16) & 15) * 4];
      union { unsigned int u[4]; bf16x8 v; } pk;
      pk.u[0] = pack2bf(u0[0], u0[1]);
      pk.u[1] = pack2bf(u0[2], u0[3]);
      pk.u[2] = pack2bf(u1[0], u1[1]);
      pk.u[3] = pack2bf(u1[2], u1[3]);
      a[half] = pk.v;
    }
#pragma unroll
    for (int nt = 0; nt < 8; nt++) {
      int col = nt * 16 + l16;
#pragma unroll
      for (int half = 0; half < 2; half++) {
        int lc = half * 4 + g;
        bf16x8 bf = *(const bf16x8*)&wtt[b][col * 64 + ((lc ^ (col & 7)) & 7) * 8];
        acc[nt] = __builtin_amdgcn_mfma_f32_16x16x32_bf16(a[half], bf, acc[nt], 0, 0, 0);
      }
    }
  }
#undef STAGE_QKV

  const float* bias = (p == 0) ? bq : ((p == 1) ? bk : bv);
  float mult = (p == 0) ? (0.08838834764831845f * 1.44269504088896340f) : 1.0f;
  if (p < 2) {
    unsigned short* outp = (p == 0) ? qs : kkv;
#pragma unroll
    for (int nt = 0; nt < 8; nt++) {
      int col = nt * 16 + l16;
      float bsv = bias[col];
#pragma unroll
      for (int r = 0; r < 4; r++) {
        int row = mt * 64 + w * 16 + g * 4 + r;
        outp[(size_t)row * DH + col] = f2bf((acc[nt][r] + bsv) * mult);
      }
    }
  } else {
#pragma unroll
    for (int nt = 0; nt < 8; nt++) {
      int col = nt * 16 + l16;
      float bsv = bias[col] * 0.0625f;  // bv/16 to match Wv/16
      int row0 = mt * 64 + w * 16 + g * 4;
      uint2 uv;
      uv.x = pack2bf(acc[nt][0] + bsv, acc[nt][1] + bsv);
      uv.y = pack2bf(acc[nt][2] + bsv, acc[nt][3] + bsv);
      *(uint2*)(&vt[(size_t)col * NTOK + row0]) = uv;  // V stored transposed
    }
  }
}

// -------------------------- flash attention, shift-free softmax, dbuf pipeline
// grid (8 sp, 64 qt), block 512 = 8 waves = 2 kg x 4 qg. Block: 128 q-rows x 64-key
// chunks; wave (kg,qg): 32 q-rows (2 q-sets) x 32 keys. 80KB LDS -> 2 blocks/CU
// = 16 waves/CU = 4/SIMD (VGPR<=128 via launch_bounds).
// S^T = K@Q^T: each lane's values belong to one q-row (col=lane&15).
// Scores bounded: |s| <= |q||k|*scale*log2e <= 5.4 -> exp2(s) in (0, ~42]; no max needed.
__global__ __launch_bounds__(512, 4) void k_flash(const unsigned short* __restrict__ qs,
                                                  const unsigned short* __restrict__ kkv,
                                                  const unsigned short* __restrict__ vt,
                                                  _Float16* __restrict__ opart,
                                                  float* __restrict__ lpart) {
  __shared__ unsigned short smem[40960];  // 80KB: kt 2x16K | vtl 2x16K | pscr 16K
  unsigned short* kt = smem;              // [2][64*128] K tiles, swizzled
  unsigned short* vtl = smem + 16384;     // [2][128*64] V^T tiles, swizzled
  unsigned short* pscr = smem + 32768;    // [8 waves][2 qs][512] P scratch
  int sp = blockIdx.x, qt = blockIdx.y;   // sp fastest -> XCD-pinned K/V
  int tid = threadIdx.x;
  int w = tid >> 6, lane = tid & 63, l16 = lane & 15, g = lane >> 4;
  int kg = w & 1, qg = w >> 1;
  int sw4 = (l16 >> 1) & 3;  // P-scratch chunk swizzle (rows 64B)

  bf16x8 qf[2][4];
  int qbase = qt * 128 + qg * 32;
#pragma unroll
  for (int q2 = 0; q2 < 2; q2++)
#pragma unroll
    for (int f = 0; f < 4; f++)
      qf[q2][f] = *(const bf16x8*)(&qs[(size_t)(qbase + q2 * 16 + l16) * DH + f * 32 + g * 8]);

  int pcK[4];
#pragma unroll
  for (int f = 0; f < 4; f++) {
    int lc = f * 4 + g;
    pcK[f] = (lc & 8) | ((lc ^ l16) & 7);
  }
  int pcV = ((kg * 4 + g) ^ l16) & 7;  // round-6 pcV[kb] with kb := kg
  int pcP = (g ^ sw4) & 3;

  // Staging identical to round 6, re-partitioned across 8 waves (2 segs each).
#define STAGE_FLASH(buf, chunk)                                                  \
  {                                                                              \
    int key0 = (chunk) * 64;                                                     \
    _Pragma("unroll") for (int ii = 0; ii < 2; ii++) {                           \
      int i = w * 2 + ii;                                                        \
      int krow = 4 * i + (lane >> 4);                                            \
      int klc = ((lane & 15) & 8) | (((lane & 15) ^ krow) & 7);                  \
      gl2lds16(&kkv[(size_t)(key0 + krow) * DH + klc * 8],                       \
               &kt[(buf)*8192 + i * 512]);                                       \
      int vrow = 8 * i + (lane >> 3);                                            \
      int vlc = ((lane & 7) ^ vrow) & 7;                                         \
      gl2lds16(&vt[(size_t)vrow * NTOK + key0 + vlc * 8],                        \
               &vtl[(buf)*8192 + i * 512]);                                      \
    }                                                                            \
  }

  f32x4 zero = {0.f, 0.f, 0.f, 0.f};
  f32x4 o[2][8];
#pragma unroll
  for (int q2 = 0; q2 < 2; q2++)
#pragma unroll
    for (int dt = 0; dt < 8; dt++) o[q2][dt] = zero;
  float l[2] = {0.f, 0.f};

  int c0 = sp * CPS;
  STAGE_FLASH(0, c0);

  for (int it = 0; it < CPS; it++) {
    int b = it & 1;
    __syncthreads();  // drains own vmcnt -> tile b ready; prev reads of b^1 done
    if (it + 1 < CPS) STAGE_FLASH(b ^ 1, c0 + it + 1);

    // ---- S^T = K @ Q^T over this wave's 32-key half (kg), both q-sets share K-frags
    f32x4 s[2][2];
#pragma unroll
    for (int q2 = 0; q2 < 2; q2++)
#pragma unroll
      for (int mt = 0; mt < 2; mt++) s[q2][mt] = zero;
    __builtin_amdgcn_s_setprio(1);
#pragma unroll
    for (int mt = 0; mt < 2; mt++) {
      bf16x8 kf[4];
#pragma unroll
      for (int f = 0; f < 4; f++)
        kf[f] = *(const bf16x8*)(&kt[b * 8192 + (kg * 32 + mt * 16 + l16) * 128 + pcK[f] * 8]);
#pragma unroll
      for (int f = 0; f < 4; f++) {
        s[0][mt] = __builtin_amdgcn_mfma_f32_16x16x32_bf16(kf[f], qf[0][f], s[0][mt], 0, 0, 0);
        s[1][mt] = __builtin_amdgcn_mfma_f32_16x16x32_bf16(kf[f], qf[1][f], s[1][mt], 0, 0, 0);
      }
    }
    __builtin_amdgcn_s_setprio(0);

    // ---- shift-free softmax: p = exp2(s), accumulate sum, pack to pscr
    // Row layout: [q=l16][32 keys] = 64B row, 4 chunks of 16B, chunk idx XOR sw4.
#pragma unroll
    for (int q2 = 0; q2 < 2; q2++) {
      unsigned short* pw = &pscr[(w * 2 + q2) * 512];
      float ssum = 0.f;
#pragma unroll
      for (int mt = 0; mt < 2; mt++) {
        float p0 = __builtin_amdgcn_exp2f(s[q2][mt][0]);
        float p1 = __builtin_amdgcn_exp2f(s[q2][mt][1]);
        float p2 = __builtin_amdgcn_exp2f(s[q2][mt][2]);
        float p3 = __builtin_amdgcn_exp2f(s[q2][mt][3]);
        ssum += (p0 + p1) + (p2 + p3);
        uint2 uv;
        uv.x = pack2bf(p0, p1);
        uv.y = pack2bf(p2, p3);
        int ch = ((mt * 2 + (g >> 1)) ^ sw4) & 3;
        *(uint2*)(&pw[l16 * 32 + ch * 8 + (g & 1) * 4]) = uv;
      }
      l[q2] += ssum;
    }

    // ---- P^T B-frags (per-wave scratch: lgkmcnt orders, no barrier)
    bf16x8 pb[2];
#pragma unroll
    for (int q2 = 0; q2 < 2; q2++)
      pb[q2] = *(const bf16x8*)(&pscr[(w * 2 + q2) * 512 + l16 * 32 + pcP * 8]);

    // ---- O^T += V^T @ P^T over this wave's 32-key half, V-frags shared across q-sets
    __builtin_amdgcn_s_setprio(1);
#pragma unroll
    for (int dt = 0; dt < 8; dt++) {
      bf16x8 vf = *(const bf16x8*)(&vtl[b * 8192 + (dt * 16 + l16) * 64 + pcV * 8]);
      o[0][dt] = __builtin_amdgcn_mfma_f32_16x16x32_bf16(vf, pb[0], o[0][dt], 0, 0, 0);
      o[1][dt] = __builtin_amdgcn_mfma_f32_16x16x32_bf16(vf, pb[1], o[1][dt], 0, 0, 0);
    }
    __builtin_amdgcn_s_setprio(0);
  }
#undef STAGE_FLASH

  // ---- cross-kg reduction through LDS (once per block), then epilogue.
  // osc: 64KB over kt+vtl region, [qg][qs][dt][lane][4] floats - linear per lane.
  __syncthreads();  // all tile reads done; safe to reuse LDS
  float* osc = (float*)smem;
  float* lsc = (float*)pscr;
  if (kg == 1) {
#pragma unroll
    for (int q2 = 0; q2 < 2; q2++) {
#pragma unroll
      for (int dt = 0; dt < 8; dt++)
        *(f32x4*)&osc[(((qg * 2 + q2) * 8 + dt) << 8) + lane * 4] = o[q2][dt];
      lsc[(qg * 2 + q2) * 64 + lane] = l[q2];
    }
  }
  __syncthreads();
  if (kg == 0) {
#pragma unroll
    for (int q2 = 0; q2 < 2; q2++) {
      l[q2] += lsc[(qg * 2 + q2) * 64 + lane];
      l[q2] += __shfl_xor(l[q2], 16);
      l[q2] += __shfl_xor(l[q2], 32);
      int qrow = qbase + q2 * 16 + l16;
      size_t obase = ((size_t)sp * NTOK + qrow) * DH;
#pragma unroll
      for (int dt = 0; dt < 8; dt++) {
        f32x4 t = *(const f32x4*)&osc[(((qg * 2 + q2) * 8 + dt) << 8) + lane * 4];
        union { _Float16 h[4]; uint2 u; } pk;
        pk.h[0] = (_Float16)(o[q2][dt][0] + t[0]);
        pk.h[1] = (_Float16)(o[q2][dt][1] + t[1]);
        pk.h[2] = (_Float16)(o[q2][dt][2] + t[2]);
        pk.h[3] = (_Float16)(o[q2][dt][3] + t[3]);
        *(uint2*)(&opart[obase + dt * 16 + g * 4]) = pk.u;
      }
      if (g == 0) lpart[sp * NTOK + qrow] = l[q2];
    }
  }
}

// ---------------------------------------------------------------- split merge
__global__ __launch_bounds__(256) void k_merge(const _Float16* __restrict__ opart,
                                               const float* __restrict__ lpart,
                                               float* __restrict__ out) {
  int gid = blockIdx.x * 256 + threadIdx.x;  // 0 .. 8192*64-1, 2 cols/thread
  int row = gid >> 6, cp = gid & 63;
  float den = 0.f, n0 = 0.f, n1 = 0.f;
#pragma unroll
  for (int s = 0; s < NSPLIT; s++) {
    den += lpart[s * NTOK + row];
    union { unsigned int u; _Float16 h[2]; } v;
    v.u = *(const unsigned int*)&opart[((size_t)s * NTOK + row) * DH + cp * 2];
    n0 += (float)v.h[0];
    n1 += (float)v.h[1];
  }
  float inv = 16.0f / den;  // x16 undoes V/16
  *(float2*)&out[(size_t)row * DH + cp * 2] = make_float2(n0 * inv, n1 * inv);
}

// ---------------------------------------------------------------- launch
extern "C" void kernel_launch(void* const* d_in, const int* in_sizes, int n_in,
                              void* d_out, int out_size, void* d_ws, size_t ws_size,
                              hipStream_t stream) {
  const float* x  = (const float*)d_in[0];
  const float* Wq = (const float*)d_in[1];
  const float* bq = (const float*)d_in[2];
  const float* Wk = (const float*)d_in[3];
  const float* bk = (const float*)d_in[4];
  const float* Wv = (const float*)d_in[5];
  const float* bv = (const float*)d_in[6];
  float* out = (float*)d_out;

  char* ws = (char*)d_ws;
  _Float16*       opart = (_Float16*)(ws);                  // 8*8192*128*2 = 16777216
  unsigned short* wt  = (unsigned short*)(ws + 16777216);   // 768 KB
  unsigned short* qsb = (unsigned short*)(ws + 17563648);   // 2 MB
  unsigned short* kkb = (unsigned short*)(ws + 19660800);   // 2 MB
  unsigned short* vtb = (unsigned short*)(ws + 21757952);   // 2 MB
  float* lpart = (float*)(ws + 23855104);                   // 256 KB -> total ~23 MB

  k_build_wt<<<dim3(32, 3), 256, 0, stream>>>(Wq, Wk, Wv, wt);
  k_qkv<<<dim3(128, 3), 256, 0, stream>>>(x, wt, bq, bk, bv, qsb, kkb, vtb);
  k_flash<<<dim3(NSPLIT, 64), 512, 0, stream>>>(qsb, kkb, vtb, opart, lpart);
  k_merge<<<2048, 256, 0, stream>>>(opart, lpart, out);
}

// Round 5
// 153.634 us; speedup vs baseline: 1.2355x; 1.2355x over previous
//
#include <hip/hip_runtime.h>

// out = softmax((x@Wq+bq)(x@Wk+bk)^T / sqrt(128)) @ (x@Wv+bv), N=8192, fp32.
//
// Round 9 (= round 8 with the register-spill fixed):
//  - k_flash: 512-thread blocks, 8 waves = 2 key-groups (kg) x 4 q-groups (qg),
//    80KB LDS -> 2 blocks/CU = 16 waves/CU = 4 waves/SIMD.
//    __launch_bounds__(512, 2): round-8's (512,4) forced VGPR=64 against ~100 of
//    live state -> scratch spill (WRITE_SIZE 16.6->62.7MB, FETCH 10->40MB, 86us).
//    (512,2) caps at 256; actual ~100 -> no spill, occupancy unchanged (LDS-bound).
//    Per-wave shape = round-6 (q2=2, 32 keys via kg); round-6/7 proven swizzles.
//  - k_qkv: round-4 shape (M-tile 64, grid (128,3)) - staging-volume optimal.
//  - k_build_wt: coalesced LDS-transpose of W -> wt bf16 [3][128][1024]; Wv pre-scaled 1/16.
//  - softmax shift-free (|s|<=5.4 so exp2 never overflows); sp fastest -> XCD-pinned K/V.
//  - k_merge: out = 16 * sum(opart) / sum(l)   (16 undoes the V/16 scaling).

typedef __attribute__((ext_vector_type(8))) short bf16x8;
typedef __attribute__((ext_vector_type(4))) float f32x4;

#define NTOK 8192
#define DMODEL 1024
#define DH 128
#define NSPLIT 8
#define CPS 16  // chunks (of 64 keys) per split

__device__ __forceinline__ unsigned short f2bf(float f) {
  unsigned int u = __builtin_bit_cast(unsigned int, f);
  u += 0x7fffu + ((u >> 16) & 1u);
  return (unsigned short)(u >> 16);
}

__device__ __forceinline__ unsigned int pack2bf(float a, float b) {
  return (unsigned int)f2bf(a) | ((unsigned int)f2bf(b) << 16);
}

__device__ __forceinline__ void gl2lds16(const void* gp, void* lp) {
  const __attribute__((address_space(1))) unsigned int* g =
      (const __attribute__((address_space(1))) unsigned int*)gp;
  __attribute__((address_space(3))) unsigned int* l =
      (__attribute__((address_space(3))) unsigned int*)lp;
  __builtin_amdgcn_global_load_lds(g, l, 16, 0, 0);
}

// ------------------- W [1024][128] -> wt bf16 [128][1024], coalesced transpose
__global__ __launch_bounds__(256) void k_build_wt(const float* __restrict__ Wq,
                                                  const float* __restrict__ Wk,
                                                  const float* __restrict__ Wv,
                                                  unsigned short* __restrict__ wt) {
  __shared__ unsigned short tile[32 * 130];
  int k0 = blockIdx.x * 32;  // grid (32, 3)
  int p = blockIdx.y;
  int t = threadIdx.x;
  const float* W = (p == 0) ? Wq : ((p == 1) ? Wk : Wv);
  float vscale = (p == 2) ? 0.0625f : 1.0f;  // V/16: bounds fp16 partials; merge x16
#pragma unroll
  for (int i = 0; i < 16; i++) {
    int e = i * 256 + t;
    int n = e & 127, kk = e >> 7;
    tile[kk * 130 + n] = f2bf(W[(size_t)(k0 + kk) * DH + n] * vscale);
  }
  __syncthreads();
#pragma unroll
  for (int i = 0; i < 16; i++) {
    int e = i * 256 + t;
    int kk = e & 31, n = e >> 5;
    wt[(size_t)(p * DH + n) * DMODEL + k0 + kk] = tile[kk * 130 + n];
  }
}

// ------------------------------- QKV GEMM, dbuf single-barrier, x fp32 in LDS
// grid (128, 3), block 256. M-tile 64, N=128, BK=64.  (round-4 shape)
__global__ __launch_bounds__(256, 2) void k_qkv(const float* __restrict__ x,
                                                const unsigned short* __restrict__ wt,
                                                const float* __restrict__ bq,
                                                const float* __restrict__ bk,
                                                const float* __restrict__ bv,
                                                unsigned short* __restrict__ qs,
                                                unsigned short* __restrict__ kkv,
                                                unsigned short* __restrict__ vt) {
  __shared__ float xt[2][64 * 64];             // fp32 x-tile, XOR-swizzled, 16 KB each
  __shared__ unsigned short wtt[2][128 * 64];  // bf16 W^T tile, XOR-swizzled, 16 KB each
  int mt = blockIdx.x, p = blockIdx.y;
  int tid = threadIdx.x;
  int w = tid >> 6, lane = tid & 63, l16 = lane & 15, g = lane >> 4;

#define STAGE_QKV(buf, k0)                                                     \
  {                                                                            \
    _Pragma("unroll") for (int r = 0; r < 4; r++) {                            \
      int seg = r * 4 + w;                                                     \
      int xr = seg * 4 + (lane >> 4);                                          \
      int xlc = ((lane & 15) ^ (xr & 15)) & 15;                                \
      gl2lds16(&x[(size_t)(mt * 64 + xr) * DMODEL + (k0) + xlc * 4],           \
               &xt[buf][seg * 256]);                                           \
      int wc = seg * 8 + (lane >> 3);                                          \
      int wlc = ((lane & 7) ^ (wc & 7)) & 7;                                   \
      gl2lds16(&wt[(size_t)(p * DH + wc) * DMODEL + (k0) + wlc * 8],           \
               &wtt[buf][seg * 512]);                                          \
    }                                                                          \
  }

  f32x4 zero = {0.f, 0.f, 0.f, 0.f};
  f32x4 acc[8];
#pragma unroll
  for (int i = 0; i < 8; i++) acc[i] = zero;

  STAGE_QKV(0, 0);
  int arow = w * 16 + l16;
  for (int kt2 = 0; kt2 < 16; kt2++) {
    int b = kt2 & 1;
    __syncthreads();  // own vmcnt(0) drain -> tiles ready; all waves past prev reads
    if (kt2 < 15) STAGE_QKV(b ^ 1, (kt2 + 1) * 64);

    bf16x8 a[2];
#pragma unroll
    for (int half = 0; half < 2; half++) {
      int lc0 = half * 8 + g * 2;
      const f32x4 u0 = *(const f32x4*)&xt[b][arow * 64 + ((lc0 ^ l16) & 15) * 4];
      const f32x4 u1 = *(const f32x4*)&xt[b][arow * 64 + (((lc0 + 1) ^ l16) & 15) * 4];
      union { unsigned int u[4]; bf16x8 v; } pk;
      pk.u[0] = pack2bf(u0[0], u0[1]);
      pk.u[1] = pack2bf(u0[2], u0[3]);
      pk.u[2] = pack2bf(u1[0], u1[1]);
      pk.u[3] = pack2bf(u1[2], u1[3]);
      a[half] = pk.v;
    }
#pragma unroll
    for (int nt = 0; nt < 8; nt++) {
      int col = nt * 16 + l16;
#pragma unroll
      for (int half = 0; half < 2; half++) {
        int lc = half * 4 + g;
        bf16x8 bf = *(const bf16x8*)&wtt[b][col * 64 + ((lc ^ (col & 7)) & 7) * 8];
        acc[nt] = __builtin_amdgcn_mfma_f32_16x16x32_bf16(a[half], bf, acc[nt], 0, 0, 0);
      }
    }
  }
#undef STAGE_QKV

  const float* bias = (p == 0) ? bq : ((p == 1) ? bk : bv);
  float mult = (p == 0) ? (0.08838834764831845f * 1.44269504088896340f) : 1.0f;
  if (p < 2) {
    unsigned short* outp = (p == 0) ? qs : kkv;
#pragma unroll
    for (int nt = 0; nt < 8; nt++) {
      int col = nt * 16 + l16;
      float bsv = bias[col];
#pragma unroll
      for (int r = 0; r < 4; r++) {
        int row = mt * 64 + w * 16 + g * 4 + r;
        outp[(size_t)row * DH + col] = f2bf((acc[nt][r] + bsv) * mult);
      }
    }
  } else {
#pragma unroll
    for (int nt = 0; nt < 8; nt++) {
      int col = nt * 16 + l16;
      float bsv = bias[col] * 0.0625f;  // bv/16 to match Wv/16
      int row0 = mt * 64 + w * 16 + g * 4;
      uint2 uv;
      uv.x = pack2bf(acc[nt][0] + bsv, acc[nt][1] + bsv);
      uv.y = pack2bf(acc[nt][2] + bsv, acc[nt][3] + bsv);
      *(uint2*)(&vt[(size_t)col * NTOK + row0]) = uv;  // V stored transposed
    }
  }
}

// -------------------------- flash attention, shift-free softmax, dbuf pipeline
// grid (8 sp, 64 qt), block 512 = 8 waves = 2 kg x 4 qg. Block: 128 q-rows x 64-key
// chunks; wave (kg,qg): 32 q-rows (2 q-sets) x 32 keys. 80KB LDS -> 2 blocks/CU
// = 16 waves/CU = 4/SIMD. launch_bounds(512,2): VGPR cap 256, actual ~100 (the
// (512,4)=64-VGPR cap caused a catastrophic spill in round 8).
// S^T = K@Q^T: each lane's values belong to one q-row (col=lane&15).
// Scores bounded: |s| <= |q||k|*scale*log2e <= 5.4 -> exp2(s) in (0, ~42]; no max needed.
__global__ __launch_bounds__(512, 2) void k_flash(const unsigned short* __restrict__ qs,
                                                  const unsigned short* __restrict__ kkv,
                                                  const unsigned short* __restrict__ vt,
                                                  _Float16* __restrict__ opart,
                                                  float* __restrict__ lpart) {
  __shared__ unsigned short smem[40960];  // 80KB: kt 2x16K | vtl 2x16K | pscr 16K
  unsigned short* kt = smem;              // [2][64*128] K tiles, swizzled
  unsigned short* vtl = smem + 16384;     // [2][128*64] V^T tiles, swizzled
  unsigned short* pscr = smem + 32768;    // [8 waves][2 qs][512] P scratch
  int sp = blockIdx.x, qt = blockIdx.y;   // sp fastest -> XCD-pinned K/V
  int tid = threadIdx.x;
  int w = tid >> 6, lane = tid & 63, l16 = lane & 15, g = lane >> 4;
  int kg = w & 1, qg = w >> 1;
  int sw4 = (l16 >> 1) & 3;  // P-scratch chunk swizzle (rows 64B)

  bf16x8 qf[2][4];
  int qbase = qt * 128 + qg * 32;
#pragma unroll
  for (int q2 = 0; q2 < 2; q2++)
#pragma unroll
    for (int f = 0; f < 4; f++)
      qf[q2][f] = *(const bf16x8*)(&qs[(size_t)(qbase + q2 * 16 + l16) * DH + f * 32 + g * 8]);

  int pcK[4];
#pragma unroll
  for (int f = 0; f < 4; f++) {
    int lc = f * 4 + g;
    pcK[f] = (lc & 8) | ((lc ^ l16) & 7);
  }
  int pcV = ((kg * 4 + g) ^ l16) & 7;  // round-6 pcV[kb] with kb := kg
  int pcP = (g ^ sw4) & 3;

  // Staging identical to round 6, re-partitioned across 8 waves (2 segs each).
#define STAGE_FLASH(buf, chunk)                                                  \
  {                                                                              \
    int key0 = (chunk) * 64;                                                     \
    _Pragma("unroll") for (int ii = 0; ii < 2; ii++) {                           \
      int i = w * 2 + ii;                                                        \
      int krow = 4 * i + (lane >> 4);                                            \
      int klc = ((lane & 15) & 8) | (((lane & 15) ^ krow) & 7);                  \
      gl2lds16(&kkv[(size_t)(key0 + krow) * DH + klc * 8],                       \
               &kt[(buf)*8192 + i * 512]);                                       \
      int vrow = 8 * i + (lane >> 3);                                            \
      int vlc = ((lane & 7) ^ vrow) & 7;                                         \
      gl2lds16(&vt[(size_t)vrow * NTOK + key0 + vlc * 8],                        \
               &vtl[(buf)*8192 + i * 512]);                                      \
    }                                                                            \
  }

  f32x4 zero = {0.f, 0.f, 0.f, 0.f};
  f32x4 o[2][8];
#pragma unroll
  for (int q2 = 0; q2 < 2; q2++)
#pragma unroll
    for (int dt = 0; dt < 8; dt++) o[q2][dt] = zero;
  float l[2] = {0.f, 0.f};

  int c0 = sp * CPS;
  STAGE_FLASH(0, c0);

  for (int it = 0; it < CPS; it++) {
    int b = it & 1;
    __syncthreads();  // drains own vmcnt -> tile b ready; prev reads of b^1 done
    if (it + 1 < CPS) STAGE_FLASH(b ^ 1, c0 + it + 1);

    // ---- S^T = K @ Q^T over this wave's 32-key half (kg), both q-sets share K-frags
    f32x4 s[2][2];
#pragma unroll
    for (int q2 = 0; q2 < 2; q2++)
#pragma unroll
      for (int mt = 0; mt < 2; mt++) s[q2][mt] = zero;
    __builtin_amdgcn_s_setprio(1);
#pragma unroll
    for (int mt = 0; mt < 2; mt++) {
      bf16x8 kf[4];
#pragma unroll
      for (int f = 0; f < 4; f++)
        kf[f] = *(const bf16x8*)(&kt[b * 8192 + (kg * 32 + mt * 16 + l16) * 128 + pcK[f] * 8]);
#pragma unroll
      for (int f = 0; f < 4; f++) {
        s[0][mt] = __builtin_amdgcn_mfma_f32_16x16x32_bf16(kf[f], qf[0][f], s[0][mt], 0, 0, 0);
        s[1][mt] = __builtin_amdgcn_mfma_f32_16x16x32_bf16(kf[f], qf[1][f], s[1][mt], 0, 0, 0);
      }
    }
    __builtin_amdgcn_s_setprio(0);

    // ---- shift-free softmax: p = exp2(s), accumulate sum, pack to pscr
    // Row layout: [q=l16][32 keys] = 64B row, 4 chunks of 16B, chunk idx XOR sw4.
#pragma unroll
    for (int q2 = 0; q2 < 2; q2++) {
      unsigned short* pw = &pscr[(w * 2 + q2) * 512];
      float ssum = 0.f;
#pragma unroll
      for (int mt = 0; mt < 2; mt++) {
        float p0 = __builtin_amdgcn_exp2f(s[q2][mt][0]);
        float p1 = __builtin_amdgcn_exp2f(s[q2][mt][1]);
        float p2 = __builtin_amdgcn_exp2f(s[q2][mt][2]);
        float p3 = __builtin_amdgcn_exp2f(s[q2][mt][3]);
        ssum += (p0 + p1) + (p2 + p3);
        uint2 uv;
        uv.x = pack2bf(p0, p1);
        uv.y = pack2bf(p2, p3);
        int ch = ((mt * 2 + (g >> 1)) ^ sw4) & 3;
        *(uint2*)(&pw[l16 * 32 + ch * 8 + (g & 1) * 4]) = uv;
      }
      l[q2] += ssum;
    }

    // ---- P^T B-frags (per-wave scratch: lgkmcnt orders, no barrier)
    bf16x8 pb[2];
#pragma unroll
    for (int q2 = 0; q2 < 2; q2++)
      pb[q2] = *(const bf16x8*)(&pscr[(w * 2 + q2) * 512 + l16 * 32 + pcP * 8]);

    // ---- O^T += V^T @ P^T over this wave's 32-key half, V-frags shared across q-sets
    __builtin_amdgcn_s_setprio(1);
#pragma unroll
    for (int dt = 0; dt < 8; dt++) {
      bf16x8 vf = *(const bf16x8*)(&vtl[b * 8192 + (dt * 16 + l16) * 64 + pcV * 8]);
      o[0][dt] = __builtin_amdgcn_mfma_f32_16x16x32_bf16(vf, pb[0], o[0][dt], 0, 0, 0);
      o[1][dt] = __builtin_amdgcn_mfma_f32_16x16x32_bf16(vf, pb[1], o[1][dt], 0, 0, 0);
    }
    __builtin_amdgcn_s_setprio(0);
  }
#undef STAGE_FLASH

  // ---- cross-kg reduction through LDS (once per block), then epilogue.
  // osc: 64KB over kt+vtl region, [qg][qs][dt][lane][4] floats - linear per lane.
  __syncthreads();  // all tile reads done; safe to reuse LDS
  float* osc = (float*)smem;
  float* lsc = (float*)pscr;
  if (kg == 1) {
#pragma unroll
    for (int q2 = 0; q2 < 2; q2++) {
#pragma unroll
      for (int dt = 0; dt < 8; dt++)
        *(f32x4*)&osc[(((qg * 2 + q2) * 8 + dt) << 8) + lane * 4] = o[q2][dt];
      lsc[(qg * 2 + q2) * 64 + lane] = l[q2];
    }
  }
  __syncthreads();
  if (kg == 0) {
#pragma unroll
    for (int q2 = 0; q2 < 2; q2++) {
      l[q2] += lsc[(qg * 2 + q2) * 64 + lane];
      l[q2] += __shfl_xor(l[q2], 16);
      l[q2] += __shfl_xor(l[q2], 32);
      int qrow = qbase + q2 * 16 + l16;
      size_t obase = ((size_t)sp * NTOK + qrow) * DH;
#pragma unroll
      for (int dt = 0; dt < 8; dt++) {
        f32x4 t = *(const f32x4*)&osc[(((qg * 2 + q2) * 8 + dt) << 8) + lane * 4];
        union { _Float16 h[4]; uint2 u; } pk;
        pk.h[0] = (_Float16)(o[q2][dt][0] + t[0]);
        pk.h[1] = (_Float16)(o[q2][dt][1] + t[1]);
        pk.h[2] = (_Float16)(o[q2][dt][2] + t[2]);
        pk.h[3] = (_Float16)(o[q2][dt][3] + t[3]);
        *(uint2*)(&opart[obase + dt * 16 + g * 4]) = pk.u;
      }
      if (g == 0) lpart[sp * NTOK + qrow] = l[q2];
    }
  }
}

// ---------------------------------------------------------------- split merge
__global__ __launch_bounds__(256) void k_merge(const _Float16* __restrict__ opart,
                                               const float* __restrict__ lpart,
                                               float* __restrict__ out) {
  int gid = blockIdx.x * 256 + threadIdx.x;  // 0 .. 8192*64-1, 2 cols/thread
  int row = gid >> 6, cp = gid & 63;
  float den = 0.f, n0 = 0.f, n1 = 0.f;
#pragma unroll
  for (int s = 0; s < NSPLIT; s++) {
    den += lpart[s * NTOK + row];
    union { unsigned int u; _Float16 h[2]; } v;
    v.u = *(const unsigned int*)&opart[((size_t)s * NTOK + row) * DH + cp * 2];
    n0 += (float)v.h[0];
    n1 += (float)v.h[1];
  }
  float inv = 16.0f / den;  // x16 undoes V/16
  *(float2*)&out[(size_t)row * DH + cp * 2] = make_float2(n0 * inv, n1 * inv);
}

// ---------------------------------------------------------------- launch
extern "C" void kernel_launch(void* const* d_in, const int* in_sizes, int n_in,
                              void* d_out, int out_size, void* d_ws, size_t ws_size,
                              hipStream_t stream) {
  const float* x  = (const float*)d_in[0];
  const float* Wq = (const float*)d_in[1];
  const float* bq = (const float*)d_in[2];
  const float* Wk = (const float*)d_in[3];
  const float* bk = (const float*)d_in[4];
  const float* Wv = (const float*)d_in[5];
  const float* bv = (const float*)d_in[6];
  float* out = (float*)d_out;

  char* ws = (char*)d_ws;
  _Float16*       opart = (_Float16*)(ws);                  // 8*8192*128*2 = 16777216
  unsigned short* wt  = (unsigned short*)(ws + 16777216);   // 768 KB
  unsigned short* qsb = (unsigned short*)(ws + 17563648);   // 2 MB
  unsigned short* kkb = (unsigned short*)(ws + 19660800);   // 2 MB
  unsigned short* vtb = (unsigned short*)(ws + 21757952);   // 2 MB
  float* lpart = (float*)(ws + 23855104);                   // 256 KB -> total ~23 MB

  k_build_wt<<<dim3(32, 3), 256, 0, stream>>>(Wq, Wk, Wv, wt);
  k_qkv<<<dim3(128, 3), 256, 0, stream>>>(x, wt, bq, bk, bv, qsb, kkb, vtb);
  k_flash<<<dim3(NSPLIT, 64), 512, 0, stream>>>(qsb, kkb, vtb, opart, lpart);
  k_merge<<<2048, 256, 0, stream>>>(opart, lpart, out);
}

// Round 6
// 145.000 us; speedup vs baseline: 1.3090x; 1.0595x over previous
//
#include <hip/hip_runtime.h>

// out = softmax((x@Wq+bq)(x@Wk+bk)^T / sqrt(128)) @ (x@Wv+bv), N=8192, fp32.
//
// Round 10 (= round-6 structure + counted-vmcnt pipeline, T3/T4):
//  - k_flash & k_qkv: replaced __syncthreads() (which drains vmcnt(0) -> every
//    wave stalls on the just-issued global_load_lds batch each iter) with
//    2-deep prefetch + raw barriers: STAGE(0);STAGE(1); loop { vmcnt(8);
//    s_barrier; compute; lgkmcnt(0); s_barrier; STAGE(b, it+2) }.
//    vmcnt never 0 mid-loop; each tile's 8 loads/wave get a full iteration to
//    land. sched_barrier(0) after the wait (rule #18); lgkmcnt(0) before the
//    2nd barrier closes the ds_read-vs-overwrite window.
//  - k_flash shape = round-6 best (256 thr, 4 waves, 64-key chunks, 80KB LDS,
//    2 blocks/CU; setprio around MFMA clusters, +5% confirmed). Rounds 7-9
//    showed wave-count shuffles don't help: the drain was the bubble.
//  - k_qkv: round-4 shape (M-tile 64, grid (128,3)) - staging-volume optimal.
//  - k_build_wt: coalesced LDS-transpose of W -> wt bf16 [3][128][1024]; Wv /16.
//  - softmax shift-free (|s|<=5.4 so exp2 never overflows); sp fastest -> XCD-pinned K/V.
//  - k_merge: out = 16 * sum(opart) / sum(l)   (16 undoes the V/16 scaling).

typedef __attribute__((ext_vector_type(8))) short bf16x8;
typedef __attribute__((ext_vector_type(4))) float f32x4;

#define NTOK 8192
#define DMODEL 1024
#define DH 128
#define NSPLIT 8
#define CPS 16  // chunks (of 64 keys) per split

__device__ __forceinline__ unsigned short f2bf(float f) {
  unsigned int u = __builtin_bit_cast(unsigned int, f);
  u += 0x7fffu + ((u >> 16) & 1u);
  return (unsigned short)(u >> 16);
}

__device__ __forceinline__ unsigned int pack2bf(float a, float b) {
  return (unsigned int)f2bf(a) | ((unsigned int)f2bf(b) << 16);
}

__device__ __forceinline__ void gl2lds16(const void* gp, void* lp) {
  const __attribute__((address_space(1))) unsigned int* g =
      (const __attribute__((address_space(1))) unsigned int*)gp;
  __attribute__((address_space(3))) unsigned int* l =
      (__attribute__((address_space(3))) unsigned int*)lp;
  __builtin_amdgcn_global_load_lds(g, l, 16, 0, 0);
}

// ------------------- W [1024][128] -> wt bf16 [128][1024], coalesced transpose
__global__ __launch_bounds__(256) void k_build_wt(const float* __restrict__ Wq,
                                                  const float* __restrict__ Wk,
                                                  const float* __restrict__ Wv,
                                                  unsigned short* __restrict__ wt) {
  __shared__ unsigned short tile[32 * 130];
  int k0 = blockIdx.x * 32;  // grid (32, 3)
  int p = blockIdx.y;
  int t = threadIdx.x;
  const float* W = (p == 0) ? Wq : ((p == 1) ? Wk : Wv);
  float vscale = (p == 2) ? 0.0625f : 1.0f;  // V/16: bounds fp16 partials; merge x16
#pragma unroll
  for (int i = 0; i < 16; i++) {
    int e = i * 256 + t;
    int n = e & 127, kk = e >> 7;
    tile[kk * 130 + n] = f2bf(W[(size_t)(k0 + kk) * DH + n] * vscale);
  }
  __syncthreads();
#pragma unroll
  for (int i = 0; i < 16; i++) {
    int e = i * 256 + t;
    int kk = e & 31, n = e >> 5;
    wt[(size_t)(p * DH + n) * DMODEL + k0 + kk] = tile[kk * 130 + n];
  }
}

// ------------------------------- QKV GEMM, counted-vmcnt dbuf, x fp32 in LDS
// grid (128, 3), block 256. M-tile 64, N=128, BK=64.
__global__ __launch_bounds__(256, 2) void k_qkv(const float* __restrict__ x,
                                                const unsigned short* __restrict__ wt,
                                                const float* __restrict__ bq,
                                                const float* __restrict__ bk,
                                                const float* __restrict__ bv,
                                                unsigned short* __restrict__ qs,
                                                unsigned short* __restrict__ kkv,
                                                unsigned short* __restrict__ vt) {
  __shared__ float xt[2][64 * 64];             // fp32 x-tile, XOR-swizzled, 16 KB each
  __shared__ unsigned short wtt[2][128 * 64];  // bf16 W^T tile, XOR-swizzled, 16 KB each
  int mt = blockIdx.x, p = blockIdx.y;
  int tid = threadIdx.x;
  int w = tid >> 6, lane = tid & 63, l16 = lane & 15, g = lane >> 4;

#define STAGE_QKV(buf, k0)                                                     \
  {                                                                            \
    _Pragma("unroll") for (int r = 0; r < 4; r++) {                            \
      int seg = r * 4 + w;                                                     \
      int xr = seg * 4 + (lane >> 4);                                          \
      int xlc = ((lane & 15) ^ (xr & 15)) & 15;                                \
      gl2lds16(&x[(size_t)(mt * 64 + xr) * DMODEL + (k0) + xlc * 4],           \
               &xt[buf][seg * 256]);                                           \
      int wc = seg * 8 + (lane >> 3);                                          \
      int wlc = ((lane & 7) ^ (wc & 7)) & 7;                                   \
      gl2lds16(&wt[(size_t)(p * DH + wc) * DMODEL + (k0) + wlc * 8],           \
               &wtt[buf][seg * 512]);                                          \
    }                                                                          \
  }

  f32x4 zero = {0.f, 0.f, 0.f, 0.f};
  f32x4 acc[8];
#pragma unroll
  for (int i = 0; i < 8; i++) acc[i] = zero;

  STAGE_QKV(0, 0);       // 8 loads/wave
  STAGE_QKV(1, 64);      // 16 in flight
  int arow = w * 16 + l16;
  for (int kt2 = 0; kt2 < 16; kt2++) {
    int b = kt2 & 1;
    // tile kt2's 8 loads (issued 2 iters ago) must land; 8 newer stay in flight
    if (kt2 < 15)
      asm volatile("s_waitcnt vmcnt(8)\n\ts_barrier" ::: "memory");
    else
      asm volatile("s_waitcnt vmcnt(0)\n\ts_barrier" ::: "memory");
    __builtin_amdgcn_sched_barrier(0);

    bf16x8 a[2];
#pragma unroll
    for (int half = 0; half < 2; half++) {
      int lc0 = half * 8 + g * 2;
      const f32x4 u0 = *(const f32x4*)&xt[b][arow * 64 + ((lc0 ^ l16) & 15) * 4];
      const f32x4 u1 = *(const f32x4*)&xt[b][arow * 64 + (((lc0 + 1) ^ l16) & 15) * 4];
      union { unsigned int u[4]; bf16x8 v; } pk;
      pk.u[0] = pack2bf(u0[0], u0[1]);
      pk.u[1] = pack2bf(u0[2], u0[3]);
      pk.u[2] = pack2bf(u1[0], u1[1]);
      pk.u[3] = pack2bf(u1[2], u1[3]);
      a[half] = pk.v;
    }
#pragma unroll
    for (int nt = 0; nt < 8; nt++) {
      int col = nt * 16 + l16;
#pragma unroll
      for (int half = 0; half < 2; half++) {
        int lc = half * 4 + g;
        bf16x8 bf = *(const bf16x8*)&wtt[b][col * 64 + ((lc ^ (col & 7)) & 7) * 8];
        acc[nt] = __builtin_amdgcn_mfma_f32_16x16x32_bf16(a[half], bf, acc[nt], 0, 0, 0);
      }
    }

    // all waves done reading buf b -> safe to overwrite
    asm volatile("s_waitcnt lgkmcnt(0)\n\ts_barrier" ::: "memory");
    if (kt2 + 2 < 16) STAGE_QKV(b, (kt2 + 2) * 64);
  }
#undef STAGE_QKV

  const float* bias = (p == 0) ? bq : ((p == 1) ? bk : bv);
  float mult = (p == 0) ? (0.08838834764831845f * 1.44269504088896340f) : 1.0f;
  if (p < 2) {
    unsigned short* outp = (p == 0) ? qs : kkv;
#pragma unroll
    for (int nt = 0; nt < 8; nt++) {
      int col = nt * 16 + l16;
      float bsv = bias[col];
#pragma unroll
      for (int r = 0; r < 4; r++) {
        int row = mt * 64 + w * 16 + g * 4 + r;
        outp[(size_t)row * DH + col] = f2bf((acc[nt][r] + bsv) * mult);
      }
    }
  } else {
#pragma unroll
    for (int nt = 0; nt < 8; nt++) {
      int col = nt * 16 + l16;
      float bsv = bias[col] * 0.0625f;  // bv/16 to match Wv/16
      int row0 = mt * 64 + w * 16 + g * 4;
      uint2 uv;
      uv.x = pack2bf(acc[nt][0] + bsv, acc[nt][1] + bsv);
      uv.y = pack2bf(acc[nt][2] + bsv, acc[nt][3] + bsv);
      *(uint2*)(&vt[(size_t)col * NTOK + row0]) = uv;  // V stored transposed
    }
  }
}

// -------------------------- flash attention, shift-free softmax, counted-vmcnt
// grid (8 sp, 64 qt), block 256 = 4 waves; per wave 32 q-rows (2 q-sets), BN=64.
// S^T = K@Q^T: each lane's values belong to one q-row (col=lane&15).
// Scores bounded: |s| <= |q||k|*scale*log2e <= 5.4 -> exp2(s) in (0, ~42]; no max needed.
__global__ __launch_bounds__(256, 2) void k_flash(const unsigned short* __restrict__ qs,
                                                  const unsigned short* __restrict__ kkv,
                                                  const unsigned short* __restrict__ vt,
                                                  _Float16* __restrict__ opart,
                                                  float* __restrict__ lpart) {
  __shared__ unsigned short kt[2][64 * 128];     // K tiles, swizzled, 16 KB each
  __shared__ unsigned short vtl[2][128 * 64];    // V^T tiles, swizzled, 16 KB each
  __shared__ unsigned short pscr[4 * 2 * 1024];  // per-wave/q-set P scratch, 16 KB
  int sp = blockIdx.x, qt = blockIdx.y;          // sp fastest -> XCD-pinned K/V
  int tid = threadIdx.x;
  int w = tid >> 6, lane = tid & 63, l16 = lane & 15, g = lane >> 4;
  int swz2 = (l16 & 7) ^ ((l16 >> 3) << 1);

  bf16x8 qf[2][4];
  int qbase = qt * 128 + w * 32;
#pragma unroll
  for (int q2 = 0; q2 < 2; q2++)
#pragma unroll
    for (int f = 0; f < 4; f++)
      qf[q2][f] = *(const bf16x8*)(&qs[(size_t)(qbase + q2 * 16 + l16) * DH + f * 32 + g * 8]);

  int pcK[4], pcV[2], pcP[2];
#pragma unroll
  for (int f = 0; f < 4; f++) {
    int lc = f * 4 + g;
    pcK[f] = (lc & 8) | ((lc ^ l16) & 7);
  }
#pragma unroll
  for (int kb = 0; kb < 2; kb++) {
    int lc = kb * 4 + g;
    pcV[kb] = (lc ^ l16) & 7;
    pcP[kb] = (lc ^ swz2) & 7;
  }

#define STAGE_FLASH(buf, chunk)                                                 \
  {                                                                             \
    int key0 = (chunk) * 64;                                                    \
    _Pragma("unroll") for (int ii = 0; ii < 4; ii++) {                          \
      int i = w * 4 + ii;                                                       \
      int krow = 4 * i + (lane >> 4);                                           \
      int klc = ((lane & 15) & 8) | (((lane & 15) ^ krow) & 7);                 \
      gl2lds16(&kkv[(size_t)(key0 + krow) * DH + klc * 8], &kt[buf][i * 512]);  \
      int vrow = 8 * i + (lane >> 3);                                           \
      int vlc = ((lane & 7) ^ vrow) & 7;                                        \
      gl2lds16(&vt[(size_t)vrow * NTOK + key0 + vlc * 8], &vtl[buf][i * 512]);  \
    }                                                                           \
  }

  f32x4 zero = {0.f, 0.f, 0.f, 0.f};
  f32x4 o[2][8];
#pragma unroll
  for (int q2 = 0; q2 < 2; q2++)
#pragma unroll
    for (int dt = 0; dt < 8; dt++) o[q2][dt] = zero;
  float l[2] = {0.f, 0.f};

  int c0 = sp * CPS;
  STAGE_FLASH(0, c0);      // 8 loads/wave
  STAGE_FLASH(1, c0 + 1);  // 16 in flight

  for (int it = 0; it < CPS; it++) {
    int b = it & 1;
    // tile b's 8 staging loads (issued 2 iters ago) must land; 8 newer stay in flight
    if (it < CPS - 1)
      asm volatile("s_waitcnt vmcnt(8)\n\ts_barrier" ::: "memory");
    else
      asm volatile("s_waitcnt vmcnt(0)\n\ts_barrier" ::: "memory");
    __builtin_amdgcn_sched_barrier(0);

    // ---- S^T = K @ Q^T, both q-sets share K-frags
    f32x4 s[2][4];
#pragma unroll
    for (int q2 = 0; q2 < 2; q2++)
#pragma unroll
      for (int mt = 0; mt < 4; mt++) s[q2][mt] = zero;
    __builtin_amdgcn_s_setprio(1);
#pragma unroll
    for (int mt = 0; mt < 4; mt++) {
      bf16x8 kf[4];
#pragma unroll
      for (int f = 0; f < 4; f++)
        kf[f] = *(const bf16x8*)(&kt[b][(mt * 16 + l16) * 128 + pcK[f] * 8]);
#pragma unroll
      for (int f = 0; f < 4; f++) {
        s[0][mt] = __builtin_amdgcn_mfma_f32_16x16x32_bf16(kf[f], qf[0][f], s[0][mt], 0, 0, 0);
        s[1][mt] = __builtin_amdgcn_mfma_f32_16x16x32_bf16(kf[f], qf[1][f], s[1][mt], 0, 0, 0);
      }
    }
    __builtin_amdgcn_s_setprio(0);

    // ---- shift-free softmax: p = exp2(s), accumulate sum, pack to pscr
#pragma unroll
    for (int q2 = 0; q2 < 2; q2++) {
      unsigned short* pw = &pscr[(w * 2 + q2) * 1024];
      float ssum = 0.f;
#pragma unroll
      for (int mt = 0; mt < 4; mt++) {
        float p0 = __builtin_amdgcn_exp2f(s[q2][mt][0]);
        float p1 = __builtin_amdgcn_exp2f(s[q2][mt][1]);
        float p2 = __builtin_amdgcn_exp2f(s[q2][mt][2]);
        float p3 = __builtin_amdgcn_exp2f(s[q2][mt][3]);
        ssum += (p0 + p1) + (p2 + p3);
        uint2 uv;
        uv.x = pack2bf(p0, p1);
        uv.y = pack2bf(p2, p3);
        int ch = ((mt * 2 + (g >> 1)) ^ swz2) & 7;
        *(uint2*)(&pw[l16 * 64 + ch * 8 + (g & 1) * 4]) = uv;
      }
      l[q2] += ssum;
    }

    // ---- P^T B-frags (per-wave scratch: lgkmcnt orders, no barrier)
    bf16x8 pb[2][2];
#pragma unroll
    for (int q2 = 0; q2 < 2; q2++)
#pragma unroll
      for (int kb = 0; kb < 2; kb++)
        pb[q2][kb] = *(const bf16x8*)(&pscr[(w * 2 + q2) * 1024 + l16 * 64 + pcP[kb] * 8]);

    // ---- O^T += V^T @ P^T, V-frags shared across q-sets
    __builtin_amdgcn_s_setprio(1);
#pragma unroll
    for (int dt = 0; dt < 8; dt++)
#pragma unroll
      for (int kb = 0; kb < 2; kb++) {
        bf16x8 vf = *(const bf16x8*)(&vtl[b][(dt * 16 + l16) * 64 + pcV[kb] * 8]);
        o[0][dt] = __builtin_amdgcn_mfma_f32_16x16x32_bf16(vf, pb[0][kb], o[0][dt], 0, 0, 0);
        o[1][dt] = __builtin_amdgcn_mfma_f32_16x16x32_bf16(vf, pb[1][kb], o[1][dt], 0, 0, 0);
      }
    __builtin_amdgcn_s_setprio(0);

    // all waves done reading buf b -> safe to overwrite
    asm volatile("s_waitcnt lgkmcnt(0)\n\ts_barrier" ::: "memory");
    if (it + 2 < CPS) STAGE_FLASH(b, c0 + it + 2);
  }
#undef STAGE_FLASH

  // ---- epilogue: unnormalized partials (O^T lane: qrow=l16, d=dt*16+g*4+r)
#pragma unroll
  for (int q2 = 0; q2 < 2; q2++) {
    l[q2] += __shfl_xor(l[q2], 16);
    l[q2] += __shfl_xor(l[q2], 32);
    int qrow = qbase + q2 * 16 + l16;
    size_t obase = ((size_t)sp * NTOK + qrow) * DH;
#pragma unroll
    for (int dt = 0; dt < 8; dt++) {
      union { _Float16 h[4]; uint2 u; } pk;
      pk.h[0] = (_Float16)o[q2][dt][0];
      pk.h[1] = (_Float16)o[q2][dt][1];
      pk.h[2] = (_Float16)o[q2][dt][2];
      pk.h[3] = (_Float16)o[q2][dt][3];
      *(uint2*)(&opart[obase + dt * 16 + g * 4]) = pk.u;
    }
    if (g == 0) lpart[sp * NTOK + qrow] = l[q2];
  }
}

// ---------------------------------------------------------------- split merge
__global__ __launch_bounds__(256) void k_merge(const _Float16* __restrict__ opart,
                                               const float* __restrict__ lpart,
                                               float* __restrict__ out) {
  int gid = blockIdx.x * 256 + threadIdx.x;  // 0 .. 8192*64-1, 2 cols/thread
  int row = gid >> 6, cp = gid & 63;
  float den = 0.f, n0 = 0.f, n1 = 0.f;
#pragma unroll
  for (int s = 0; s < NSPLIT; s++) {
    den += lpart[s * NTOK + row];
    union { unsigned int u; _Float16 h[2]; } v;
    v.u = *(const unsigned int*)&opart[((size_t)s * NTOK + row) * DH + cp * 2];
    n0 += (float)v.h[0];
    n1 += (float)v.h[1];
  }
  float inv = 16.0f / den;  // x16 undoes V/16
  *(float2*)&out[(size_t)row * DH + cp * 2] = make_float2(n0 * inv, n1 * inv);
}

// ---------------------------------------------------------------- launch
extern "C" void kernel_launch(void* const* d_in, const int* in_sizes, int n_in,
                              void* d_out, int out_size, void* d_ws, size_t ws_size,
                              hipStream_t stream) {
  const float* x  = (const float*)d_in[0];
  const float* Wq = (const float*)d_in[1];
  const float* bq = (const float*)d_in[2];
  const float* Wk = (const float*)d_in[3];
  const float* bk = (const float*)d_in[4];
  const float* Wv = (const float*)d_in[5];
  const float* bv = (const float*)d_in[6];
  float* out = (float*)d_out;

  char* ws = (char*)d_ws;
  _Float16*       opart = (_Float16*)(ws);                  // 8*8192*128*2 = 16777216
  unsigned short* wt  = (unsigned short*)(ws + 16777216);   // 768 KB
  unsigned short* qsb = (unsigned short*)(ws + 17563648);   // 2 MB
  unsigned short* kkb = (unsigned short*)(ws + 19660800);   // 2 MB
  unsigned short* vtb = (unsigned short*)(ws + 21757952);   // 2 MB
  float* lpart = (float*)(ws + 23855104);                   // 256 KB -> total ~23 MB

  k_build_wt<<<dim3(32, 3), 256, 0, stream>>>(Wq, Wk, Wv, wt);
  k_qkv<<<dim3(128, 3), 256, 0, stream>>>(x, wt, bq, bk, bv, qsb, kkb, vtb);
  k_flash<<<dim3(NSPLIT, 64), 256, 0, stream>>>(qsb, kkb, vtb, opart, lpart);
  k_merge<<<2048, 256, 0, stream>>>(opart, lpart, out);
}